// Round 5
// baseline (260.764 us; speedup 1.0000x reference)
//
#include <hip/hip_runtime.h>

// ICFM: out[s] = sum_{t: seg_ids[t]==s} ( intr_W[intr_idxs[t]] / intr_divs[t]
//                                         * dot(vecs[f0[t]], vecs[f1[t]]) + intr_b[0] )
// T = 1048576, NUM_SEGMENTS = 16384, VEC = 64 floats (256 B/row), table 128 MB.
//
// R4 finding: dur == FETCH_SIZE / 2.7 TB/s across all variants -> fetch-bound.
// R5: column-split two-phase gather. Phase p reads only float4s [8p, 8p+8) of
// each row (128 B), so the random working set per phase is 64 MB (vs 32 MB
// aggregate L2), roughly doubling L2 hit rate. All 2048 blocks are co-resident
// so phases align grid-wide. Partial dots commute into the same LDS bins.
// 8 lanes per interaction; per-lane partials into bins[seg-seg0][lane8] via
// fire-and-forget LDS atomics (no cross-lane reduction chain - R2 lesson).

#define BLOCK 256
#define CHUNK 512   // interactions per block (2048 blocks, all co-resident)
#define SMAX  64    // LDS segment window (avg span ~8; global-atomic fallback)
#define U     4     // interactions per 8-lane group per iteration

__global__ __launch_bounds__(BLOCK) void icfm_kernel(
    const int*   __restrict__ intr_idxs,
    const float* __restrict__ intr_divs,
    const int*   __restrict__ feat_idxs,   // [T*2] flat pairs
    const int*   __restrict__ seg_ids,     // sorted
    const float4* __restrict__ vecs,       // [N_FEATS][16] float4
    const float* __restrict__ intr_W,
    const float* __restrict__ intr_b,
    float*       __restrict__ out,
    int n, int num_segments)
{
    __shared__ float bins[SMAX][8];
    {
        float* bf = &bins[0][0];
        for (int i = threadIdx.x; i < SMAX * 8; i += BLOCK) bf[i] = 0.0f;
    }
    __syncthreads();

    const int chunk_start = blockIdx.x * CHUNK;
    const int first_t = chunk_start < n ? chunk_start : (n - 1);
    const int seg0 = seg_ids[first_t];
    // 16 partial-adds per interaction (8 lanes x 2 phases)
    const float b16 = intr_b[0] * (1.0f / 16.0f);

    const int lane8 = threadIdx.x & 7;
    const int group = threadIdx.x >> 3;   // 32 groups per block

    for (int p = 0; p < 2; ++p) {
        const int coff = p * 8 + lane8;   // which float4 of the row

        for (int i = 0; i < CHUNK; i += 32 * U) {
            const int tb = chunk_start + i + group;

            // ---- load phase: issue all gathers before any consumption ----
            float4 a[U], c[U];
            float  w[U], dv[U];
            int    sg[U];
            bool   ok[U];
            #pragma unroll
            for (int u = 0; u < U; ++u) {
                int t = tb + 32 * u;
                ok[u] = (t < n);
                int tc = ok[u] ? t : first_t;           // safe clamp
                int f0 = feat_idxs[2 * tc];
                int f1 = feat_idxs[2 * tc + 1];
                a[u]  = vecs[(size_t)f0 * 16 + coff];
                c[u]  = vecs[(size_t)f1 * 16 + coff];
                w[u]  = intr_W[intr_idxs[tc]];
                dv[u] = intr_divs[tc];
                sg[u] = seg_ids[tc];
            }

            // ---- compute: no cross-lane ops, fire-and-forget atomics ----
            #pragma unroll
            for (int u = 0; u < U; ++u) {
                if (!ok[u]) continue;
                float d = a[u].x * c[u].x + a[u].y * c[u].y
                        + a[u].z * c[u].z + a[u].w * c[u].w;
                float val = w[u] / dv[u] * d + b16;     // per-lane-phase partial
                int local = sg[u] - seg0;
                if ((unsigned)local < (unsigned)SMAX)
                    atomicAdd(&bins[local][lane8], val); // LDS atomic, no return
                else
                    atomicAdd(&out[sg[u]], val);         // rare overflow fallback
            }
        }
    }
    __syncthreads();

    // ---- flush: column-reduce each bin, one global atomic per bin ----
    if (threadIdx.x < SMAX) {
        float v = 0.0f;
        #pragma unroll
        for (int j = 0; j < 8; ++j) v += bins[threadIdx.x][j];
        int s = seg0 + threadIdx.x;
        if (v != 0.0f && s < num_segments)
            atomicAdd(&out[s], v);
    }
}

extern "C" void kernel_launch(void* const* d_in, const int* in_sizes, int n_in,
                              void* d_out, int out_size, void* d_ws, size_t ws_size,
                              hipStream_t stream) {
    const int*    intr_idxs = (const int*)   d_in[0];
    const float*  intr_divs = (const float*) d_in[1];
    const int*    feat_idxs = (const int*)   d_in[2];
    const int*    seg_ids   = (const int*)   d_in[3];
    const float4* vecs      = (const float4*)d_in[4];
    const float*  intr_W    = (const float*) d_in[5];
    const float*  intr_b    = (const float*) d_in[6];
    float* out = (float*)d_out;

    const int n = in_sizes[0];             // T
    const int num_segments = out_size;     // 16384

    // d_out is re-poisoned to 0xAA before every timed launch
    (void)hipMemsetAsync(d_out, 0, (size_t)out_size * sizeof(float), stream);

    const int grid = (n + CHUNK - 1) / CHUNK;
    icfm_kernel<<<grid, BLOCK, 0, stream>>>(intr_idxs, intr_divs, feat_idxs,
                                            seg_ids, vecs, intr_W, intr_b,
                                            out, n, num_segments);
}